// Round 3
// baseline (103.446 us; speedup 1.0000x reference)
//
#include <hip/hip_runtime.h>
#include <math.h>

#define BB 1024
#define TT 196
#define NC 10

// quad_perm DPP helper. CTRL byte: sel0 | sel1<<2 | sel2<<4 | sel3<<6
template <int CTRL>
__device__ __forceinline__ float qp(float v) {
    return __int_as_float(__builtin_amdgcn_update_dpp(
        0, __float_as_int(v), CTRL, 0xF, 0xF, true));
}
#define QP_XOR3 0x1B  // [3,2,1,0]
#define QP_XOR1 0xB1  // [1,0,3,2]
#define QP_BC0  0x00  // [0,0,0,0]

__device__ __forceinline__ float rcp_f(float v) {
    return __builtin_amdgcn_rcpf(v);
}

// ---------------- Kernel 1: quanvolution (+ optional angle-x-part precompute) ----
// One thread per (b,t) patch. U and W reads are wave-uniform -> scalar loads.
// AXP=true: writes axp[t][b][g][q] = b[q]+rx[q] + sum_j W[q][j]*z_j  (16 floats)
// AXP=false: writes seq[t][b][q] = z_q (4 floats)
template <bool AXP>
__global__ void quanv_kernel(const float* __restrict__ x,
                             const float* __restrict__ U_re,
                             const float* __restrict__ U_im,
                             const float* __restrict__ Wf, const float* __restrict__ bf,
                             const float* __restrict__ Wi, const float* __restrict__ bi,
                             const float* __restrict__ Wg, const float* __restrict__ bg,
                             const float* __restrict__ Wo, const float* __restrict__ bo,
                             const float* __restrict__ rxf, const float* __restrict__ rxi,
                             const float* __restrict__ rxg, const float* __restrict__ rxo,
                             float* __restrict__ ws) {
    int tid = blockIdx.x * blockDim.x + threadIdx.x;
    if (tid >= BB * TT) return;
    int b = tid / TT;
    int t = tid - b * TT;
    int r = t / 14, c = t - r * 14;
    const float* img = x + (size_t)b * 784;

    float cc[4], ss[4];
    {
        float a0 = img[(2 * r) * 28 + 2 * c];
        float a1 = img[(2 * r) * 28 + 2 * c + 1];
        float a2 = img[(2 * r + 1) * 28 + 2 * c];
        float a3 = img[(2 * r + 1) * 28 + 2 * c + 1];
        __sincosf(0.5f * a0, &ss[0], &cc[0]);
        __sincosf(0.5f * a1, &ss[1], &cc[1]);
        __sincosf(0.5f * a2, &ss[2], &cc[2]);
        __sincosf(0.5f * a3, &ss[3], &cc[3]);
    }

    // product-state amplitudes (real), wire0 = MSB of 4-bit index
    float a[16];
#pragma unroll
    for (int j = 0; j < 16; ++j) {
        float v = ((j >> 3) & 1) ? ss[0] : cc[0];
        v *= ((j >> 2) & 1) ? ss[1] : cc[1];
        v *= ((j >> 1) & 1) ? ss[2] : cc[2];
        v *= ((j >> 0) & 1) ? ss[3] : cc[3];
        a[j] = v;
    }

    float z0 = 0.f, z1 = 0.f, z2 = 0.f, z3 = 0.f;
#pragma unroll
    for (int j = 0; j < 16; ++j) {
        float vr = 0.f, vi = 0.f;
#pragma unroll
        for (int k = 0; k < 16; ++k) {
            vr = fmaf(U_re[j * 16 + k], a[k], vr);   // uniform addr -> s_load
            vi = fmaf(U_im[j * 16 + k], a[k], vi);
        }
        float p = vr * vr + vi * vi;
        z0 += ((j >> 3) & 1) ? -p : p;
        z1 += ((j >> 2) & 1) ? -p : p;
        z2 += ((j >> 1) & 1) ? -p : p;
        z3 += ((j >> 0) & 1) ? -p : p;
    }

    if (AXP) {
        float4* axv = reinterpret_cast<float4*>(ws + (((size_t)t * BB + b) << 4));
#define DO_GATE(G, W, BV, RX)                                                 \
        {                                                                     \
            float a0v, a1v, a2v, a3v;                                         \
            _Pragma("unroll")                                                 \
            for (int q = 0; q < 4; ++q) {                                     \
                float av = BV[q] + RX[q];                                     \
                av = fmaf(W[q * 8 + 0], z0, av);                              \
                av = fmaf(W[q * 8 + 1], z1, av);                              \
                av = fmaf(W[q * 8 + 2], z2, av);                              \
                av = fmaf(W[q * 8 + 3], z3, av);                              \
                if (q == 0) a0v = av; else if (q == 1) a1v = av;              \
                else if (q == 2) a2v = av; else a3v = av;                     \
            }                                                                 \
            axv[G] = make_float4(a0v, a1v, a2v, a3v);                         \
        }
        DO_GATE(0, Wf, bf, rxf)
        DO_GATE(1, Wi, bi, rxi)
        DO_GATE(2, Wg, bg, rxg)
        DO_GATE(3, Wo, bo, rxo)
#undef DO_GATE
    } else {
        *reinterpret_cast<float4*>(ws + ((size_t)t * BB + b) * 4) =
            make_float4(z0, z1, z2, z3);
    }
}

// ---------------- Kernel 2a: QLSTM from precomputed angle x-parts ----------------
// 4 lanes per batch element, lane g owns gate g. Only h-FMAs in the loop.
__global__ __launch_bounds__(64) void qlstm_axp_kernel(
    const float* __restrict__ axp,
    const float* __restrict__ Wf, const float* __restrict__ Wi,
    const float* __restrict__ Wg, const float* __restrict__ Wo,
    const float* __restrict__ Wc, const float* __restrict__ bc,
    float* __restrict__ out) {
    int tid = blockIdx.x * 64 + threadIdx.x;
    int b = tid >> 2;
    int g = tid & 3;
    if (b >= BB) return;

    const float* W;
    if (g == 0)      W = Wf;
    else if (g == 1) W = Wi;
    else if (g == 2) W = Wg;
    else             W = Wo;

    float wh[4][4];
#pragma unroll
    for (int q = 0; q < 4; ++q)
#pragma unroll
        for (int j = 0; j < 4; ++j) wh[q][j] = W[q * 8 + 4 + j];

    const float m1 = (g == 2) ? 2.f : 1.f;
    const float m2 = m1;
    const float a2 = (g == 2) ? -1.f : 0.f;

    float h[4] = {0.f, 0.f, 0.f, 0.f};
    float c[4] = {0.f, 0.f, 0.f, 0.f};

    const float* base = axp + ((size_t)b << 4) + (g << 2);
    float4 nxt = *reinterpret_cast<const float4*>(base);
    for (int t = 0; t < TT; ++t) {
        float4 aq = nxt;
        // unconditional prefetch of t+1; row TT exists (padded ws), value unused
        nxt = *reinterpret_cast<const float4*>(base + (size_t)(t + 1) * (BB * 16));

        float axq[4] = {aq.x, aq.y, aq.z, aq.w};
        float C[4];
#pragma unroll
        for (int q = 0; q < 4; ++q) {
            // depth-3 tree: (axp + w0h0 + w1h1) + (w2h2 + w3h3)
            float p01 = fmaf(wh[q][1], h[1], fmaf(wh[q][0], h[0], axq[q]));
            float p23 = fmaf(wh[q][3], h[3], wh[q][2] * h[2]);
            C[q] = __cosf(p01 + p23);
        }
        float z[4];
        z[1] = C[0] * C[1];
        z[2] = z[1] * C[2];
        z[3] = z[2] * C[3];
        z[0] = C[1] * (C[2] * C[3]);

        float val[4];
#pragma unroll
        for (int q = 0; q < 4; ++q) {
            float e = __expf(-z[q] * m1);
            float s = rcp_f(1.f + e);
            val[q] = fmaf(s, m2, a2);
        }

#pragma unroll
        for (int q = 0; q < 4; ++q) {
            float s1 = qp<QP_XOR3>(val[q]);   // lane0<-o, lane1<-g, lane2<-i, lane3<-f
            float u  = val[q] * s1;           // lane1 = i*g
            float s2 = qp<QP_XOR1>(u);        // lane0 <- i*g
            c[q] = fmaf(val[q], c[q], s2);    // lane0: f*c + i*g
            float e2 = __expf(-2.f * c[q]);
            float th = fmaf(2.f, rcp_f(1.f + e2), -1.f);  // tanh
            float hq = s1 * th;               // lane0: o*tanh(c)
            h[q] = qp<QP_BC0>(hq);            // broadcast lane0 -> quad
        }
    }

    if (g == 0) {
        float l[NC];
        float mx = -1e30f;
#pragma unroll
        for (int k = 0; k < NC; ++k) {
            float v = bc[k];
#pragma unroll
            for (int q = 0; q < 4; ++q) v = fmaf(Wc[k * 4 + q], h[q], v);
            l[k] = v;
            mx = fmaxf(mx, v);
        }
        float se = 0.f;
#pragma unroll
        for (int k = 0; k < NC; ++k) se += __expf(l[k] - mx);
        float lse = mx + __logf(se);
#pragma unroll
        for (int k = 0; k < NC; ++k) out[(size_t)b * NC + k] = l[k] - lse;
    }
}

// ---------------- Kernel 2b: fallback (R2-proven), reads seq ----------------
__global__ __launch_bounds__(64) void qlstm_seq_kernel(
    const float* __restrict__ seq,
    const float* __restrict__ Wf, const float* __restrict__ bf,
    const float* __restrict__ Wi, const float* __restrict__ bi,
    const float* __restrict__ Wg, const float* __restrict__ bg,
    const float* __restrict__ Wo, const float* __restrict__ bo,
    const float* __restrict__ rxf, const float* __restrict__ rxi,
    const float* __restrict__ rxg, const float* __restrict__ rxo,
    const float* __restrict__ Wc, const float* __restrict__ bc,
    float* __restrict__ out) {
    int tid = blockIdx.x * 64 + threadIdx.x;
    int b = tid >> 2;
    int g = tid & 3;
    if (b >= BB) return;

    const float* W;
    const float* bb;
    const float* rx;
    if (g == 0)      { W = Wf; bb = bf; rx = rxf; }
    else if (g == 1) { W = Wi; bb = bi; rx = rxi; }
    else if (g == 2) { W = Wg; bb = bg; rx = rxg; }
    else             { W = Wo; bb = bo; rx = rxo; }

    float wx[4][4], wh[4][4], pre[4];
#pragma unroll
    for (int q = 0; q < 4; ++q) {
#pragma unroll
        for (int j = 0; j < 4; ++j) {
            wx[q][j] = W[q * 8 + j];
            wh[q][j] = W[q * 8 + 4 + j];
        }
        pre[q] = bb[q] + rx[q];
    }
    const float m1 = (g == 2) ? 2.f : 1.f;
    const float m2 = m1;
    const float a2 = (g == 2) ? -1.f : 0.f;

    float h[4] = {0.f, 0.f, 0.f, 0.f};
    float c[4] = {0.f, 0.f, 0.f, 0.f};

    float4 nxt = *reinterpret_cast<const float4*>(seq + (size_t)b * 4);
    for (int t = 0; t < TT; ++t) {
        float4 xt = nxt;
        int tn = (t + 1 < TT) ? (t + 1) : (TT - 1);
        nxt = *reinterpret_cast<const float4*>(seq + ((size_t)tn * BB + b) * 4);

        float C[4];
#pragma unroll
        for (int q = 0; q < 4; ++q) {
            float ang = pre[q];
            ang = fmaf(wx[q][0], xt.x, ang);
            ang = fmaf(wx[q][1], xt.y, ang);
            ang = fmaf(wx[q][2], xt.z, ang);
            ang = fmaf(wx[q][3], xt.w, ang);
            float p01 = fmaf(wh[q][1], h[1], fmaf(wh[q][0], h[0], ang));
            float p23 = fmaf(wh[q][3], h[3], wh[q][2] * h[2]);
            C[q] = __cosf(p01 + p23);
        }
        float z[4];
        z[1] = C[0] * C[1];
        z[2] = z[1] * C[2];
        z[3] = z[2] * C[3];
        z[0] = C[1] * (C[2] * C[3]);

        float val[4];
#pragma unroll
        for (int q = 0; q < 4; ++q) {
            float e = __expf(-z[q] * m1);
            float s = rcp_f(1.f + e);
            val[q] = fmaf(s, m2, a2);
        }
#pragma unroll
        for (int q = 0; q < 4; ++q) {
            float s1 = qp<QP_XOR3>(val[q]);
            float u  = val[q] * s1;
            float s2 = qp<QP_XOR1>(u);
            c[q] = fmaf(val[q], c[q], s2);
            float e2 = __expf(-2.f * c[q]);
            float th = fmaf(2.f, rcp_f(1.f + e2), -1.f);
            float hq = s1 * th;
            h[q] = qp<QP_BC0>(hq);
        }
    }

    if (g == 0) {
        float l[NC];
        float mx = -1e30f;
#pragma unroll
        for (int k = 0; k < NC; ++k) {
            float v = bc[k];
#pragma unroll
            for (int q = 0; q < 4; ++q) v = fmaf(Wc[k * 4 + q], h[q], v);
            l[k] = v;
            mx = fmaxf(mx, v);
        }
        float se = 0.f;
#pragma unroll
        for (int k = 0; k < NC; ++k) se += __expf(l[k] - mx);
        float lse = mx + __logf(se);
#pragma unroll
        for (int k = 0; k < NC; ++k) out[(size_t)b * NC + k] = l[k] - lse;
    }
}

extern "C" void kernel_launch(void* const* d_in, const int* in_sizes, int n_in,
                              void* d_out, int out_size, void* d_ws, size_t ws_size,
                              hipStream_t stream) {
    (void)in_sizes; (void)n_in; (void)out_size;
    const float* x    = (const float*)d_in[0];
    const float* U_re = (const float*)d_in[1];
    const float* U_im = (const float*)d_in[2];
    const float* Wf   = (const float*)d_in[3];
    const float* bf   = (const float*)d_in[4];
    const float* Wi   = (const float*)d_in[5];
    const float* bi   = (const float*)d_in[6];
    const float* Wg   = (const float*)d_in[7];
    const float* bg   = (const float*)d_in[8];
    const float* Wo   = (const float*)d_in[9];
    const float* bo   = (const float*)d_in[10];
    const float* rxf  = (const float*)d_in[11];
    const float* rxi  = (const float*)d_in[12];
    const float* rxg  = (const float*)d_in[13];
    const float* rxo  = (const float*)d_in[14];
    const float* Wc   = (const float*)d_in[15];
    const float* bc   = (const float*)d_in[16];

    float* ws  = (float*)d_ws;
    float* out = (float*)d_out;

    // axp needs (TT+1) rows of B*16 floats (one pad row for unconditional prefetch)
    size_t need_axp = (size_t)(TT + 1) * BB * 16 * sizeof(float);  // ~12.9 MB

    if (ws_size >= need_axp) {
        quanv_kernel<true><<<(BB * TT + 255) / 256, 256, 0, stream>>>(
            x, U_re, U_im, Wf, bf, Wi, bi, Wg, bg, Wo, bo,
            rxf, rxi, rxg, rxo, ws);
        qlstm_axp_kernel<<<(BB * 4) / 64, 64, 0, stream>>>(
            ws, Wf, Wi, Wg, Wo, Wc, bc, out);
    } else {
        quanv_kernel<false><<<(BB * TT + 255) / 256, 256, 0, stream>>>(
            x, U_re, U_im, Wf, bf, Wi, bi, Wg, bg, Wo, bo,
            rxf, rxi, rxg, rxo, ws);
        qlstm_seq_kernel<<<(BB * 4) / 64, 64, 0, stream>>>(
            ws, Wf, bf, Wi, bi, Wg, bg, Wo, bo,
            rxf, rxi, rxg, rxo, Wc, bc, out);
    }
}

// Round 4
// 78.335 us; speedup vs baseline: 1.3206x; 1.3206x over previous
//
#include <hip/hip_runtime.h>
#include <math.h>

#define BB 1024
#define TT 196
#define NC 10

// quad_perm DPP helper. CTRL byte: sel0 | sel1<<2 | sel2<<4 | sel3<<6
template <int CTRL>
__device__ __forceinline__ float qp(float v) {
    return __int_as_float(__builtin_amdgcn_update_dpp(
        0, __float_as_int(v), CTRL, 0xF, 0xF, true));
}
#define QP_XOR3 0x1B  // [3,2,1,0]
#define QP_XOR1 0xB1  // [1,0,3,2]
#define QP_BC0  0x00  // [0,0,0,0]

__device__ __forceinline__ float rcp_f(float v) { return __builtin_amdgcn_rcpf(v); }
// raw v_cos_f32: input in REVOLUTIONS (cos(2*pi*x)); we pre-scale weights by 1/2pi
__device__ __forceinline__ float cos_rev(float v) { return __builtin_amdgcn_cosf(v); }

// ---------------- Kernel 1: quanvolution ----------------
// One thread per (b,t), t fastest within the wave. U reads are wave-uniform
// (scalar loads). Stores seq in b-major layout: seq[b][t] float4 -> lanes
// (consecutive t) write consecutive 16B = fully coalesced.
__global__ void quanv_kernel(const float* __restrict__ x,
                             const float* __restrict__ U_re,
                             const float* __restrict__ U_im,
                             float* __restrict__ seq) {
    int tid = blockIdx.x * blockDim.x + threadIdx.x;
    if (tid >= BB * TT) return;
    int b = tid / TT;
    int t = tid - b * TT;
    int r = t / 14, c = t - r * 14;
    const float* img = x + (size_t)b * 784;

    float cc[4], ss[4];
    {
        float a0 = img[(2 * r) * 28 + 2 * c];
        float a1 = img[(2 * r) * 28 + 2 * c + 1];
        float a2 = img[(2 * r + 1) * 28 + 2 * c];
        float a3 = img[(2 * r + 1) * 28 + 2 * c + 1];
        __sincosf(0.5f * a0, &ss[0], &cc[0]);
        __sincosf(0.5f * a1, &ss[1], &cc[1]);
        __sincosf(0.5f * a2, &ss[2], &cc[2]);
        __sincosf(0.5f * a3, &ss[3], &cc[3]);
    }

    // product-state amplitudes (real), wire0 = MSB of 4-bit index
    float a[16];
#pragma unroll
    for (int j = 0; j < 16; ++j) {
        float v = ((j >> 3) & 1) ? ss[0] : cc[0];
        v *= ((j >> 2) & 1) ? ss[1] : cc[1];
        v *= ((j >> 1) & 1) ? ss[2] : cc[2];
        v *= ((j >> 0) & 1) ? ss[3] : cc[3];
        a[j] = v;
    }

    float z0 = 0.f, z1 = 0.f, z2 = 0.f, z3 = 0.f;
#pragma unroll
    for (int j = 0; j < 16; ++j) {
        float vr = 0.f, vi = 0.f;
#pragma unroll
        for (int k = 0; k < 16; ++k) {
            vr = fmaf(U_re[j * 16 + k], a[k], vr);   // uniform addr -> s_load
            vi = fmaf(U_im[j * 16 + k], a[k], vi);
        }
        float p = vr * vr + vi * vi;
        z0 += ((j >> 3) & 1) ? -p : p;
        z1 += ((j >> 2) & 1) ? -p : p;
        z2 += ((j >> 1) & 1) ? -p : p;
        z3 += ((j >> 0) & 1) ? -p : p;
    }

    *reinterpret_cast<float4*>(seq + ((size_t)b * TT + t) * 4) =
        make_float4(z0, z1, z2, z3);
}

// ---------------- Kernel 2: QLSTM, 4 lanes per batch element ----------------
// lane g owns gate g (0=f,1=i,2=g,3=o). All weights in static registers,
// pre-scaled by 1/2pi so v_cos takes revolutions directly. Nonlinearities via
// Pade[5/4] tanh (sigma(z)=0.5+0.5*tanh(z/2)) with per-lane constants:
// no exp, only rcp. 4-deep float4 prefetch pipeline hides HBM/L2 latency.
__global__ __launch_bounds__(64) void qlstm_kernel(
    const float* __restrict__ seq,
    const float* __restrict__ Wf, const float* __restrict__ bf,
    const float* __restrict__ Wi, const float* __restrict__ bi,
    const float* __restrict__ Wg, const float* __restrict__ bg,
    const float* __restrict__ Wo, const float* __restrict__ bo,
    const float* __restrict__ rxf, const float* __restrict__ rxi,
    const float* __restrict__ rxg, const float* __restrict__ rxo,
    const float* __restrict__ Wc, const float* __restrict__ bc,
    float* __restrict__ out) {
    int tid = blockIdx.x * 64 + threadIdx.x;
    int b = tid >> 2;
    int g = tid & 3;
    if (b >= BB) return;

    const float* W;
    const float* bb;
    const float* rx;
    if (g == 0)      { W = Wf; bb = bf; rx = rxf; }
    else if (g == 1) { W = Wi; bb = bi; rx = rxi; }
    else if (g == 2) { W = Wg; bb = bg; rx = rxg; }
    else             { W = Wo; bb = bo; rx = rxo; }

    const float INV2PI = 0.15915494309189535f;
    float wx[4][4], wh[4][4], pre[4];
#pragma unroll
    for (int q = 0; q < 4; ++q) {
#pragma unroll
        for (int j = 0; j < 4; ++j) {
            wx[q][j] = W[q * 8 + j] * INV2PI;
            wh[q][j] = W[q * 8 + 4 + j] * INV2PI;
        }
        pre[q] = (bb[q] + rx[q]) * INV2PI;
    }

    // Pade constants: lane g==2 -> tanh(z); others -> sigma(z)=0.5+0.5*tanh(z/2)
    const bool tn = (g == 2);
    const float n0 = tn ? 945.f : 236.25f;
    const float n1 = tn ? 105.f : 6.5625f;
    const float n2 = tn ? 1.f   : 0.015625f;
    const float d1 = tn ? 420.f : 105.f;
    const float d2 = tn ? 15.f  : 0.9375f;
    const float kk = tn ? 0.f   : 0.5f;

    float h[4] = {0.f, 0.f, 0.f, 0.f};
    float c[4] = {0.f, 0.f, 0.f, 0.f};

    const float* base = seq + (size_t)b * (TT * 4);

#define LD(T) (*reinterpret_cast<const float4*>(base + (size_t)(T) * 4))

#define STEP(XT)                                                              \
    {                                                                         \
        float C[4];                                                           \
        _Pragma("unroll")                                                     \
        for (int q = 0; q < 4; ++q) {                                         \
            float xpart = fmaf(wx[q][0], (XT).x,                              \
                          fmaf(wx[q][1], (XT).y, pre[q])) +                   \
                          fmaf(wx[q][2], (XT).z, wx[q][3] * (XT).w);          \
            float pa = fmaf(wh[q][0], h[0], wh[q][1] * h[1]);                 \
            float pb = fmaf(wh[q][2], h[2], wh[q][3] * h[3]);                 \
            C[q] = cos_rev((xpart + pa) + pb);                                \
        }                                                                     \
        float z[4];                                                           \
        z[1] = C[0] * C[1];                                                   \
        z[2] = z[1] * C[2];                                                   \
        z[3] = z[2] * C[3];                                                   \
        z[0] = C[1] * (C[2] * C[3]);                                          \
        float val[4];                                                         \
        _Pragma("unroll")                                                     \
        for (int q = 0; q < 4; ++q) {                                         \
            float w2 = z[q] * z[q];                                           \
            float nn = z[q] * fmaf(w2, fmaf(w2, n2, n1), n0);                 \
            float dd = fmaf(w2, fmaf(w2, d2, d1), 945.f);                     \
            val[q] = fmaf(nn, rcp_f(dd), kk);                                 \
        }                                                                     \
        _Pragma("unroll")                                                     \
        for (int q = 0; q < 4; ++q) {                                         \
            float s1 = qp<QP_XOR3>(val[q]);                                   \
            float u  = val[q] * s1;                                           \
            float s2 = qp<QP_XOR1>(u);                                        \
            c[q] = fmaf(val[q], c[q], s2);                                    \
            float wc = c[q] * c[q];                                           \
            float na = c[q] * fmaf(wc, fmaf(wc, 1.f, 105.f), 945.f);          \
            float da = fmaf(wc, fmaf(wc, 15.f, 420.f), 945.f);                \
            float th = na * rcp_f(da);                                        \
            h[q] = qp<QP_BC0>(s1 * th);                                       \
        }                                                                     \
    }

    float4 p0 = LD(0);
    float4 p1 = LD(1);
    float4 p2 = LD(2);
    float4 p3 = LD(3);

    for (int t = 0; t < TT; t += 4) {
        STEP(p0);
        p0 = LD((t + 4 < TT) ? t + 4 : TT - 1);
        STEP(p1);
        p1 = LD((t + 5 < TT) ? t + 5 : TT - 1);
        STEP(p2);
        p2 = LD((t + 6 < TT) ? t + 6 : TT - 1);
        STEP(p3);
        p3 = LD((t + 7 < TT) ? t + 7 : TT - 1);
    }
#undef STEP
#undef LD

    // classifier + log_softmax (lane 0 of each quad)
    if (g == 0) {
        float l[NC];
        float mx = -1e30f;
#pragma unroll
        for (int k = 0; k < NC; ++k) {
            float v = bc[k];
#pragma unroll
            for (int q = 0; q < 4; ++q) v = fmaf(Wc[k * 4 + q], h[q], v);
            l[k] = v;
            mx = fmaxf(mx, v);
        }
        float se = 0.f;
#pragma unroll
        for (int k = 0; k < NC; ++k) se += __expf(l[k] - mx);
        float lse = mx + __logf(se);
#pragma unroll
        for (int k = 0; k < NC; ++k) out[(size_t)b * NC + k] = l[k] - lse;
    }
}

extern "C" void kernel_launch(void* const* d_in, const int* in_sizes, int n_in,
                              void* d_out, int out_size, void* d_ws, size_t ws_size,
                              hipStream_t stream) {
    (void)in_sizes; (void)n_in; (void)out_size; (void)ws_size;
    const float* x    = (const float*)d_in[0];
    const float* U_re = (const float*)d_in[1];
    const float* U_im = (const float*)d_in[2];
    const float* Wf   = (const float*)d_in[3];
    const float* bf   = (const float*)d_in[4];
    const float* Wi   = (const float*)d_in[5];
    const float* bi   = (const float*)d_in[6];
    const float* Wg   = (const float*)d_in[7];
    const float* bg   = (const float*)d_in[8];
    const float* Wo   = (const float*)d_in[9];
    const float* bo   = (const float*)d_in[10];
    const float* rxf  = (const float*)d_in[11];
    const float* rxi  = (const float*)d_in[12];
    const float* rxg  = (const float*)d_in[13];
    const float* rxo  = (const float*)d_in[14];
    const float* Wc   = (const float*)d_in[15];
    const float* bc   = (const float*)d_in[16];

    float* seq = (float*)d_ws;   // (B, T) float4, b-major = 3.2 MB
    float* out = (float*)d_out;  // (B, 10)

    quanv_kernel<<<(BB * TT + 255) / 256, 256, 0, stream>>>(x, U_re, U_im, seq);
    qlstm_kernel<<<(BB * 4) / 64, 64, 0, stream>>>(seq, Wf, bf, Wi, bi, Wg, bg,
                                                   Wo, bo, rxf, rxi, rxg, rxo,
                                                   Wc, bc, out);
}

// Round 6
// 42.071 us; speedup vs baseline: 2.4588x; 1.8620x over previous
//
#include <hip/hip_runtime.h>
#include <math.h>

#define BB 1024
#define TT 196
#define NC 10

// DPP helper. quad_perm ctrl = sel0|sel1<<2|sel2<<4|sel3<<6; row_ror:N = 0x120|N
// row_ror:N semantics (GCN/CDNA): lane i reads lane (i-N) mod 16.
template <int CTRL>
__device__ __forceinline__ float dppf(float v) {
    return __int_as_float(__builtin_amdgcn_update_dpp(
        0, __float_as_int(v), CTRL, 0xF, 0xF, true));
}
#define QP_XOR3 0x1B   // quad: [3,2,1,0]
#define QP_XOR1 0xB1   // quad: [1,0,3,2]
#define QP_BC0  0x00   // quad: [0,0,0,0]
#define ROR4    0x124  // lane <- lane-4  (brings q+... see derivation)
#define ROR8    0x128  // lane <- lane-8
#define ROR12   0x12C  // lane <- lane-12 (= lane+4 mod 16)

__device__ __forceinline__ float rcp_f(float v) { return __builtin_amdgcn_rcpf(v); }
__device__ __forceinline__ float cos_rev(float v) { return __builtin_amdgcn_cosf(v); }

// ---------------- Kernel 1: quanvolution + angle-x-part precompute ----------------
// One thread per (b,t), t fastest. U/W reads wave-uniform -> scalar loads.
// Writes axp[b][t][16]: element q*4+g = (bias_g[q]+rx_g[q] + W_g[q][:]z) / 2pi.
__global__ void quanv_kernel(const float* __restrict__ x,
                             const float* __restrict__ U_re,
                             const float* __restrict__ U_im,
                             const float* __restrict__ Wf, const float* __restrict__ bf,
                             const float* __restrict__ Wi, const float* __restrict__ bi,
                             const float* __restrict__ Wg, const float* __restrict__ bg,
                             const float* __restrict__ Wo, const float* __restrict__ bo,
                             const float* __restrict__ rxf, const float* __restrict__ rxi,
                             const float* __restrict__ rxg, const float* __restrict__ rxo,
                             float* __restrict__ axp) {
    int tid = blockIdx.x * blockDim.x + threadIdx.x;
    if (tid >= BB * TT) return;
    int b = tid / TT;
    int t = tid - b * TT;
    int r = t / 14, c = t - r * 14;
    const float* img = x + (size_t)b * 784;

    float cc[4], ss[4];
    {
        float a0 = img[(2 * r) * 28 + 2 * c];
        float a1 = img[(2 * r) * 28 + 2 * c + 1];
        float a2 = img[(2 * r + 1) * 28 + 2 * c];
        float a3 = img[(2 * r + 1) * 28 + 2 * c + 1];
        __sincosf(0.5f * a0, &ss[0], &cc[0]);
        __sincosf(0.5f * a1, &ss[1], &cc[1]);
        __sincosf(0.5f * a2, &ss[2], &cc[2]);
        __sincosf(0.5f * a3, &ss[3], &cc[3]);
    }

    float a[16];
#pragma unroll
    for (int j = 0; j < 16; ++j) {
        float v = ((j >> 3) & 1) ? ss[0] : cc[0];
        v *= ((j >> 2) & 1) ? ss[1] : cc[1];
        v *= ((j >> 1) & 1) ? ss[2] : cc[2];
        v *= ((j >> 0) & 1) ? ss[3] : cc[3];
        a[j] = v;
    }

    float z0 = 0.f, z1 = 0.f, z2 = 0.f, z3 = 0.f;
#pragma unroll
    for (int j = 0; j < 16; ++j) {
        float vr = 0.f, vi = 0.f;
#pragma unroll
        for (int k = 0; k < 16; ++k) {
            vr = fmaf(U_re[j * 16 + k], a[k], vr);   // uniform addr -> s_load
            vi = fmaf(U_im[j * 16 + k], a[k], vi);
        }
        float p = vr * vr + vi * vi;
        z0 += ((j >> 3) & 1) ? -p : p;
        z1 += ((j >> 2) & 1) ? -p : p;
        z2 += ((j >> 1) & 1) ? -p : p;
        z3 += ((j >> 0) & 1) ? -p : p;
    }

    const float INV2PI = 0.15915494309189535f;
    float4* dst = reinterpret_cast<float4*>(axp + ((size_t)(b * TT + t) << 4));
#pragma unroll
    for (int q = 0; q < 4; ++q) {
        float vf = bf[q] + rxf[q];
        vf = fmaf(Wf[q*8+0], z0, vf); vf = fmaf(Wf[q*8+1], z1, vf);
        vf = fmaf(Wf[q*8+2], z2, vf); vf = fmaf(Wf[q*8+3], z3, vf);
        float vi = bi[q] + rxi[q];
        vi = fmaf(Wi[q*8+0], z0, vi); vi = fmaf(Wi[q*8+1], z1, vi);
        vi = fmaf(Wi[q*8+2], z2, vi); vi = fmaf(Wi[q*8+3], z3, vi);
        float vg = bg[q] + rxg[q];
        vg = fmaf(Wg[q*8+0], z0, vg); vg = fmaf(Wg[q*8+1], z1, vg);
        vg = fmaf(Wg[q*8+2], z2, vg); vg = fmaf(Wg[q*8+3], z3, vg);
        float vo = bo[q] + rxo[q];
        vo = fmaf(Wo[q*8+0], z0, vo); vo = fmaf(Wo[q*8+1], z1, vo);
        vo = fmaf(Wo[q*8+2], z2, vo); vo = fmaf(Wo[q*8+3], z3, vo);
        dst[q] = make_float4(vf * INV2PI, vi * INV2PI, vg * INV2PI, vo * INV2PI);
    }
}

// ---------------- Kernel 2: QLSTM, 16 lanes per batch element ----------------
// lane = q*4+g. One (gate,qubit) per lane. Cos-products over q via row_ror
// (lane <- lane-N), LSTM combine over g via quad_perm, h exchange via
// row_ror with pre-permuted weights. One dword load/step, 14-deep prefetch.
//
// Per lane q: e1=ror4(C)=C_{q-1}; aa=C*e1=C_q C_{q-1};
//             e2=ror8(aa)=C_{q-2}C_{q-3}; e4=ror8(C)=C_{q-2}.
//   q=0: z0=C1C2C3 = e2*e1   q=1: z1=C0C1 = aa
//   q=2: z2=C0C1C2 = aa*e4   q=3: z3=C0C1C2C3 = aa*e2
// h: hq broadcast in quad; hh1=ror12(hq)=h_{q+1}, hh2=ror8=h_{q+2},
//    hh3=ror4=h_{q+3}; weights pre-permuted wh_k = W[q][4+((q+k)&3)].
__global__ __launch_bounds__(64) void qlstm16_kernel(
    const float* __restrict__ axp,
    const float* __restrict__ Wf, const float* __restrict__ Wi,
    const float* __restrict__ Wg, const float* __restrict__ Wo,
    const float* __restrict__ Wc, const float* __restrict__ bc,
    float* __restrict__ out) {
    int tid = blockIdx.x * 64 + threadIdx.x;
    int b = tid >> 4;
    int l16 = tid & 15;
    int q = l16 >> 2, g = l16 & 3;
    if (b >= BB) return;

    const float* W;
    if (g == 0)      W = Wf;
    else if (g == 1) W = Wi;
    else if (g == 2) W = Wg;
    else             W = Wo;

    const float INV2PI = 0.15915494309189535f;
    float wh0 = W[q * 8 + 4 + ((q + 0) & 3)] * INV2PI;
    float wh1 = W[q * 8 + 4 + ((q + 1) & 3)] * INV2PI;
    float wh2 = W[q * 8 + 4 + ((q + 2) & 3)] * INV2PI;
    float wh3 = W[q * 8 + 4 + ((q + 3) & 3)] * INV2PI;

    // Pade[5/4]: g==2 lane -> tanh(z); others -> sigma(z)=0.5+0.5*tanh(z/2)
    const bool tn = (g == 2);
    const float n0 = tn ? 945.f : 236.25f;
    const float n1 = tn ? 105.f : 6.5625f;
    const float n2 = tn ? 1.f   : 0.015625f;
    const float d1 = tn ? 420.f : 105.f;
    const float d2 = tn ? 15.f  : 0.9375f;
    const float kk = tn ? 0.f   : 0.5f;

    const bool q0 = (q == 0), q1 = (q == 1), q2 = (q == 2);

    float hh0 = 0.f, hh1 = 0.f, hh2 = 0.f, hh3 = 0.f, c = 0.f;
    const float* base = axp + (((size_t)b * TT) << 4) + l16;

#define LDX(T) base[(size_t)(T) << 4]

#define STEP(XP, TNEXT)                                                       \
    {                                                                         \
        float t0 = fmaf(wh0, hh0, (XP));                                      \
        float t1 = fmaf(wh3, hh3, wh2 * hh2);                                 \
        float ang = fmaf(wh1, hh1, t0) + t1;                                  \
        float C = cos_rev(ang);                                               \
        float e1 = dppf<ROR4>(C);       /* C_{q-1} */                         \
        float aa = C * e1;              /* C_q C_{q-1} */                     \
        float e2 = dppf<ROR8>(aa);      /* C_{q-2}C_{q-3} */                  \
        float e4 = dppf<ROR8>(C);       /* C_{q-2} */                         \
        float A = q0 ? e2 : aa;                                               \
        float Bv = q0 ? e1 : (q1 ? 1.0f : (q2 ? e4 : e2));                    \
        float z = A * Bv;                                                     \
        float w2 = z * z;                                                     \
        float nn = z * fmaf(w2, fmaf(w2, n2, n1), n0);                        \
        float dd = fmaf(w2, fmaf(w2, d2, d1), 945.f);                         \
        float val = fmaf(nn, rcp_f(dd), kk);                                  \
        float s1 = dppf<QP_XOR3>(val);                                        \
        float u  = val * s1;                                                  \
        float s2 = dppf<QP_XOR1>(u);                                          \
        c = fmaf(val, c, s2);           /* valid at g==0 */                   \
        float wc = c * c;                                                     \
        float na = c * fmaf(wc, fmaf(wc, 1.f, 105.f), 945.f);                 \
        float da = fmaf(wc, fmaf(wc, 15.f, 420.f), 945.f);                    \
        float th = na * rcp_f(da);                                            \
        float hq = dppf<QP_BC0>(s1 * th);   /* h_q -> whole quad */           \
        hh0 = hq;                                                             \
        hh1 = dppf<ROR12>(hq);          /* h_{q+1} */                         \
        hh2 = dppf<ROR8>(hq);           /* h_{q+2} */                         \
        hh3 = dppf<ROR4>(hq);           /* h_{q+3} */                         \
        int tp = (TNEXT) > (TT - 1) ? (TT - 1) : (TNEXT);                     \
        (XP) = LDX(tp);                                                       \
    }

    float xp0  = LDX(0),  xp1  = LDX(1),  xp2  = LDX(2),  xp3  = LDX(3);
    float xp4  = LDX(4),  xp5  = LDX(5),  xp6  = LDX(6),  xp7  = LDX(7);
    float xp8  = LDX(8),  xp9  = LDX(9),  xp10 = LDX(10), xp11 = LDX(11);
    float xp12 = LDX(12), xp13 = LDX(13);

    for (int it = 0; it < 14; ++it) {
        int itb = it * 14 + 14;
        STEP(xp0,  itb + 0)
        STEP(xp1,  itb + 1)
        STEP(xp2,  itb + 2)
        STEP(xp3,  itb + 3)
        STEP(xp4,  itb + 4)
        STEP(xp5,  itb + 5)
        STEP(xp6,  itb + 6)
        STEP(xp7,  itb + 7)
        STEP(xp8,  itb + 8)
        STEP(xp9,  itb + 9)
        STEP(xp10, itb + 10)
        STEP(xp11, itb + 11)
        STEP(xp12, itb + 12)
        STEP(xp13, itb + 13)
    }
#undef STEP
#undef LDX

    // classifier + log_softmax: lane q=0,g=0 holds hh_k = h_k
    if (l16 == 0) {
        float l[NC];
        float mx = -1e30f;
#pragma unroll
        for (int k = 0; k < NC; ++k) {
            float v = bc[k];
            v = fmaf(Wc[k * 4 + 0], hh0, v);
            v = fmaf(Wc[k * 4 + 1], hh1, v);
            v = fmaf(Wc[k * 4 + 2], hh2, v);
            v = fmaf(Wc[k * 4 + 3], hh3, v);
            l[k] = v;
            mx = fmaxf(mx, v);
        }
        float se = 0.f;
#pragma unroll
        for (int k = 0; k < NC; ++k) se += __expf(l[k] - mx);
        float lse = mx + __logf(se);
#pragma unroll
        for (int k = 0; k < NC; ++k) out[(size_t)b * NC + k] = l[k] - lse;
    }
}

extern "C" void kernel_launch(void* const* d_in, const int* in_sizes, int n_in,
                              void* d_out, int out_size, void* d_ws, size_t ws_size,
                              hipStream_t stream) {
    (void)in_sizes; (void)n_in; (void)out_size; (void)ws_size;
    const float* x    = (const float*)d_in[0];
    const float* U_re = (const float*)d_in[1];
    const float* U_im = (const float*)d_in[2];
    const float* Wf   = (const float*)d_in[3];
    const float* bf   = (const float*)d_in[4];
    const float* Wi   = (const float*)d_in[5];
    const float* bi   = (const float*)d_in[6];
    const float* Wg   = (const float*)d_in[7];
    const float* bg   = (const float*)d_in[8];
    const float* Wo   = (const float*)d_in[9];
    const float* bo   = (const float*)d_in[10];
    const float* rxf  = (const float*)d_in[11];
    const float* rxi  = (const float*)d_in[12];
    const float* rxg  = (const float*)d_in[13];
    const float* rxo  = (const float*)d_in[14];
    const float* Wc   = (const float*)d_in[15];
    const float* bc   = (const float*)d_in[16];

    float* axp = (float*)d_ws;   // (B, T, 16) = 12.85 MB
    float* out = (float*)d_out;  // (B, 10)

    quanv_kernel<<<(BB * TT + 255) / 256, 256, 0, stream>>>(
        x, U_re, U_im, Wf, bf, Wi, bi, Wg, bg, Wo, bo,
        rxf, rxi, rxg, rxo, axp);
    qlstm16_kernel<<<(BB * 16) / 64, 64, 0, stream>>>(
        axp, Wf, Wi, Wg, Wo, Wc, bc, out);
}